// Round 1
// baseline (238.814 us; speedup 1.0000x reference)
//
#include <hip/hip_runtime.h>
#include <math.h>

// Problem constants
// B=16, N=128, M=64, D=512, H=4, K=128, L=3

// Workspace layout (in floats)
#define OFF_W   0                        // w = word@Wn_w + b   : 2048*512
#define OFF_R   (2048*512)               // r = rel@Wr_w + b    : 1024*512
#define OFF_V   (OFF_R + 1024*512)       // v[d][h]             : 512*4
#define OFF_G   (OFF_V + 2048)           // G[b][h][d]          : 16*4*512
#define OFF_SW  (OFF_G + 32768)          // SW[b][h]            : 16*4

// ---------------------------------------------------------------------------
// Kernel 1: fused projections  w = word@Wn_w + Wn_b ; r = rel@Wr_w + Wr_b
// 64x64 tile, 256 threads, 4x4 microtile, BK=16.
// blocks [0,256): w (2048 rows), [256,384): r (1024 rows)
// ---------------------------------------------------------------------------
__global__ __launch_bounds__(256) void proj_gemm(
    const float* __restrict__ word, const float* __restrict__ rel,
    const float* __restrict__ Wn_w, const float* __restrict__ Wn_b,
    const float* __restrict__ Wr_w, const float* __restrict__ Wr_b,
    float* __restrict__ ws)
{
    int blk = blockIdx.x;
    const float *A, *W, *bias;
    float* C;
    int rowTile, colTile;
    if (blk < 256) {
        A = word; W = Wn_w; bias = Wn_b; C = ws + OFF_W;
        rowTile = blk >> 3; colTile = blk & 7;
    } else {
        int b2 = blk - 256;
        A = rel; W = Wr_w; bias = Wr_b; C = ws + OFF_R;
        rowTile = b2 >> 3; colTile = b2 & 7;
    }
    const int row0 = rowTile * 64, col0 = colTile * 64;

    __shared__ float As[16][68];   // [k][row], padded
    __shared__ float Bs[16][64];   // [k][col]

    const int t  = threadIdx.x;
    const int tx = t & 15, ty = t >> 4;
    const int lr = t >> 2, lk = (t & 3) << 2;   // A-tile load coords
    const int bk = t >> 4, bc = (t & 15) << 2;  // B-tile load coords

    float acc[4][4] = {};

    for (int k0 = 0; k0 < 512; k0 += 16) {
        float4 a4 = *(const float4*)(A + (size_t)(row0 + lr) * 512 + k0 + lk);
        As[lk + 0][lr] = a4.x; As[lk + 1][lr] = a4.y;
        As[lk + 2][lr] = a4.z; As[lk + 3][lr] = a4.w;
        *(float4*)&Bs[bk][bc] = *(const float4*)(W + (size_t)(k0 + bk) * 512 + col0 + bc);
        __syncthreads();
        #pragma unroll
        for (int kk = 0; kk < 16; kk++) {
            float4 av = *(float4*)&As[kk][ty << 2];
            float4 bv = *(float4*)&Bs[kk][tx << 2];
            float aa[4] = {av.x, av.y, av.z, av.w};
            float bb[4] = {bv.x, bv.y, bv.z, bv.w};
            #pragma unroll
            for (int i = 0; i < 4; i++)
                #pragma unroll
                for (int j = 0; j < 4; j++)
                    acc[i][j] = fmaf(aa[i], bb[j], acc[i][j]);
        }
        __syncthreads();
    }
    float4 bv = *(const float4*)(bias + col0 + (tx << 2));
    float bb[4] = {bv.x, bv.y, bv.z, bv.w};
    #pragma unroll
    for (int i = 0; i < 4; i++) {
        float4 o;
        o.x = acc[i][0] + bb[0]; o.y = acc[i][1] + bb[1];
        o.z = acc[i][2] + bb[2]; o.w = acc[i][3] + bb[3];
        *(float4*)(C + (size_t)(row0 + (ty << 2) + i) * 512 + col0 + (tx << 2)) = o;
    }
}

// ---------------------------------------------------------------------------
// Kernel 2: v[h,d] = sum_k lin_w[h,d,k] * score_w[h,k]  (stored as v[d][h])
// (lin_b/score_b constants cancel in softmax — skipped)
// ---------------------------------------------------------------------------
__global__ __launch_bounds__(256) void prep_v(
    const float* __restrict__ lin_w, const float* __restrict__ score_w,
    float* __restrict__ ws)
{
    int gid = blockIdx.x * 256 + threadIdx.x;  // 0..2047
    int h = gid >> 9, d = gid & 511;
    const float* lw = lin_w + (size_t)(h * 512 + d) * 128;
    const float* sw = score_w + h * 128;
    float acc = 0.f;
    #pragma unroll 4
    for (int k = 0; k < 128; k += 4) {
        float4 a = *(const float4*)(lw + k);
        float4 b = *(const float4*)(sw + k);
        acc = fmaf(a.x, b.x, acc); acc = fmaf(a.y, b.y, acc);
        acc = fmaf(a.z, b.z, acc); acc = fmaf(a.w, b.w, acc);
    }
    ws[OFF_V + d * 4 + h] = acc;
}

// ---------------------------------------------------------------------------
// Kernel 3: per (b,n): scores -> softmax -> g accumulation into G[b,h,d]
// 2048 blocks x 256 threads (4 waves)
// ---------------------------------------------------------------------------
__global__ __launch_bounds__(256) void attn_kernel(
    const float* __restrict__ mask, float* __restrict__ ws)
{
    const int bn = blockIdx.x;            // b*128 + n
    const int b = bn >> 7;
    const float* wrow  = ws + OFF_W + (size_t)bn * 512;
    const float* rbase = ws + OFF_R + (size_t)b * 64 * 512;
    const float* vbase = ws + OFF_V;
    float* G  = ws + OFF_G + (size_t)b * 2048;
    float* SW = ws + OFF_SW + b * 4;

    __shared__ float s_lds[64][4];
    __shared__ float wts_lds[64][4];
    __shared__ float sw_lds[4];

    const int t = threadIdx.x;
    const int lane = t & 63, wv = t >> 6;

    // ---- Phase 1: s[m,h] = sum_d relu(w[d]*r[m,d]) * v[h,d]
    // wave wv handles m = wv*16 .. wv*16+15 ; lane covers d = 8*lane..8*lane+7
    float wreg[8];
    {
        float4 wA = *(const float4*)(wrow + lane * 8);
        float4 wB = *(const float4*)(wrow + lane * 8 + 4);
        wreg[0] = wA.x; wreg[1] = wA.y; wreg[2] = wA.z; wreg[3] = wA.w;
        wreg[4] = wB.x; wreg[5] = wB.y; wreg[6] = wB.z; wreg[7] = wB.w;
    }
    float4 v4[8];
    #pragma unroll
    for (int jj = 0; jj < 8; jj++)
        v4[jj] = *(const float4*)(vbase + (lane * 8 + jj) * 4);

    for (int mi = 0; mi < 16; mi++) {
        int m = wv * 16 + mi;
        const float* rrow = rbase + (size_t)m * 512;
        float rreg[8];
        {
            float4 rA = *(const float4*)(rrow + lane * 8);
            float4 rB = *(const float4*)(rrow + lane * 8 + 4);
            rreg[0] = rA.x; rreg[1] = rA.y; rreg[2] = rA.z; rreg[3] = rA.w;
            rreg[4] = rB.x; rreg[5] = rB.y; rreg[6] = rB.z; rreg[7] = rB.w;
        }
        float a0 = 0.f, a1 = 0.f, a2 = 0.f, a3 = 0.f;
        #pragma unroll
        for (int jj = 0; jj < 8; jj++) {
            float had = fmaxf(wreg[jj] * rreg[jj], 0.f);
            a0 = fmaf(had, v4[jj].x, a0);
            a1 = fmaf(had, v4[jj].y, a1);
            a2 = fmaf(had, v4[jj].z, a2);
            a3 = fmaf(had, v4[jj].w, a3);
        }
        #pragma unroll
        for (int off = 32; off > 0; off >>= 1) {
            a0 += __shfl_xor(a0, off);
            a1 += __shfl_xor(a1, off);
            a2 += __shfl_xor(a2, off);
            a3 += __shfl_xor(a3, off);
        }
        if (lane == 0) {
            s_lds[m][0] = a0; s_lds[m][1] = a1;
            s_lds[m][2] = a2; s_lds[m][3] = a3;
        }
    }
    __syncthreads();

    // ---- Phase 2: softmax over m per h ; wts = softmax(s)*mask
    {
        int h = wv, m = lane;
        float s = s_lds[m][h];
        float mx = s;
        #pragma unroll
        for (int off = 32; off > 0; off >>= 1)
            mx = fmaxf(mx, __shfl_xor(mx, off));
        float e = expf(s - mx);
        float sum = e;
        #pragma unroll
        for (int off = 32; off > 0; off >>= 1)
            sum += __shfl_xor(sum, off);
        float wt = e / sum * mask[b * 64 + m];
        float swv = wt;
        #pragma unroll
        for (int off = 32; off > 0; off >>= 1)
            swv += __shfl_xor(swv, off);
        wts_lds[m][h] = wt;
        if (m == 0) sw_lds[h] = swv;
    }
    __syncthreads();

    // ---- Phase 3: g[h,d] = sum_m wts[m,h]*relu(w[d]*r[m,d]) ; atomic into G
    {
        float2 wd = *(const float2*)(wrow + t * 2);
        float g0[4] = {0.f, 0.f, 0.f, 0.f};
        float g1[4] = {0.f, 0.f, 0.f, 0.f};
        for (int m = 0; m < 64; m++) {
            float2 rv = *(const float2*)(rbase + (size_t)m * 512 + t * 2);
            float h0 = fmaxf(wd.x * rv.x, 0.f);
            float h1 = fmaxf(wd.y * rv.y, 0.f);
            float4 wt = *(const float4*)&wts_lds[m][0];
            g0[0] = fmaf(wt.x, h0, g0[0]); g1[0] = fmaf(wt.x, h1, g1[0]);
            g0[1] = fmaf(wt.y, h0, g0[1]); g1[1] = fmaf(wt.y, h1, g1[1]);
            g0[2] = fmaf(wt.z, h0, g0[2]); g1[2] = fmaf(wt.z, h1, g1[2]);
            g0[3] = fmaf(wt.w, h0, g0[3]); g1[3] = fmaf(wt.w, h1, g1[3]);
        }
        #pragma unroll
        for (int h = 0; h < 4; h++) {
            atomicAdd(&G[h * 512 + t * 2],     g0[h]);
            atomicAdd(&G[h * 512 + t * 2 + 1], g1[h]);
        }
        if (t < 4) atomicAdd(&SW[t], sw_lds[t]);
    }
}

// ---------------------------------------------------------------------------
// Kernel 4: per-batch epilogue
// headmean[h,k] = (G[b,h,:]/N)·lin_w[h,:,k] + lin_b[h,k]*SW[b,h]/N
// out = relu(headmean @ final_w + final_b); logits = out @ fc_w + fc_b
// ---------------------------------------------------------------------------
__global__ __launch_bounds__(256) void head_kernel(
    const float* __restrict__ lin_w, const float* __restrict__ lin_b,
    const float* __restrict__ final_w, const float* __restrict__ final_b,
    const float* __restrict__ fc_w, const float* __restrict__ fc_b,
    const float* __restrict__ ws, float* __restrict__ out)
{
    const int b = blockIdx.x;
    const int t = threadIdx.x;
    __shared__ float Gs[2048];
    __shared__ float hm[512];
    __shared__ float os[512];
    __shared__ float SWs[4];

    const float* G = ws + OFF_G + (size_t)b * 2048;
    #pragma unroll
    for (int i = 0; i < 8; i++) Gs[t + 256 * i] = G[t + 256 * i];
    if (t < 4) SWs[t] = ws[OFF_SW + b * 4 + t];
    __syncthreads();

    // headmean (512 outputs, 2 per thread)
    #pragma unroll
    for (int i = 0; i < 2; i++) {
        int idx = t + 256 * i;
        int h = idx >> 7, k = idx & 127;
        float acc = lin_b[h * 128 + k] * SWs[h];
        const float* lwp = lin_w + ((size_t)h * 512) * 128 + k;
        const float* gp = Gs + h * 512;
        for (int d = 0; d < 512; d++)
            acc = fmaf(gp[d], lwp[(size_t)d * 128], acc);
        hm[idx] = acc * (1.0f / 128.0f);
    }
    __syncthreads();

    // out = relu(hm @ final_w + final_b)
    #pragma unroll
    for (int i = 0; i < 2; i++) {
        int j = t + 256 * i;
        float acc = final_b[j];
        for (int d = 0; d < 512; d++)
            acc = fmaf(hm[d], final_w[(size_t)d * 512 + j], acc);
        os[j] = fmaxf(acc, 0.f);
    }
    __syncthreads();

    // logits (3 outputs, wave per output)
    if (t < 192) {
        int l = t >> 6, ln = t & 63;
        float acc = 0.f;
        for (int i = ln; i < 512; i += 64)
            acc = fmaf(os[i], fc_w[i * 3 + l], acc);
        #pragma unroll
        for (int off = 32; off > 0; off >>= 1)
            acc += __shfl_xor(acc, off);
        if (ln == 0) out[b * 3 + l] = acc + fc_b[l];
    }
}

// ---------------------------------------------------------------------------
extern "C" void kernel_launch(void* const* d_in, const int* in_sizes, int n_in,
                              void* d_out, int out_size, void* d_ws, size_t ws_size,
                              hipStream_t stream)
{
    const float* word    = (const float*)d_in[0];
    const float* rel     = (const float*)d_in[1];
    const float* mask    = (const float*)d_in[2];
    const float* Wn_w    = (const float*)d_in[3];
    const float* Wn_b    = (const float*)d_in[4];
    const float* Wr_w    = (const float*)d_in[5];
    const float* Wr_b    = (const float*)d_in[6];
    const float* lin_w   = (const float*)d_in[7];
    const float* lin_b   = (const float*)d_in[8];
    const float* score_w = (const float*)d_in[9];
    // d_in[10] score_b: cancels in softmax — unused
    const float* final_w = (const float*)d_in[11];
    const float* final_b = (const float*)d_in[12];
    const float* fc_w    = (const float*)d_in[13];
    const float* fc_b    = (const float*)d_in[14];
    float* ws  = (float*)d_ws;
    float* out = (float*)d_out;

    // zero the G / SW accumulators (ws is poisoned 0xAA each call)
    hipMemsetAsync(ws + OFF_G, 0, (32768 + 64) * sizeof(float), stream);

    proj_gemm<<<384, 256, 0, stream>>>(word, rel, Wn_w, Wn_b, Wr_w, Wr_b, ws);
    prep_v<<<8, 256, 0, stream>>>(lin_w, score_w, ws);
    attn_kernel<<<2048, 256, 0, stream>>>(mask, ws);
    head_kernel<<<16, 256, 0, stream>>>(lin_w, lin_b, final_w, final_b,
                                        fc_w, fc_b, ws, out);
}